// Round 6
// baseline (13.519 us; speedup 1.0000x reference)
//
#include <hip/hip_runtime.h>

// FastSpeech2 hard duration-based frame->token averaging.
// R14 = R13's traffic cut WITHOUT its serial chain. Key identity: rounded
// durations are <= MAX_DUR=16, so Sum(dur) <= 16*dlen, giving an entry-time
// bound UB = min(16*dlen, flen) >= Fneed from two scalar loads only.
// Frame loads predicate at UB and issue AT KERNEL ENTRY (overlapping the
// duration scan + barrier #1), removing the second serialized cold-HBM
// round-trip R13 introduced (dur load -> scan -> barrier -> Fneed -> frame
// loads). Traffic: E[UB]~3413 vs E[Fneed]~2731 frames (+5.3MB vs R13, still
// -17% vs R12's flen predicate). Everything else = R13: coalesced chunk
// loads, reg prefix, 4 DPP scans, wave-local linear-LDS prefix (no swizzle,
// no conflicts), cross-wave correction folded into the 3-point gather,
// 2 barriers total.
// Output = [B*TT token_scalar | B duration_len(float)].

namespace {
constexpr int TT = 1024;   // tokens per row
constexpr int TF = 8192;   // frames per row
constexpr int NT = 512;    // threads per block (8 waves)
constexpr int NW = NT / 64;

// Canonical GCN wave64 inclusive add-scan via DPP (VALU pipe, no LDS).
__device__ __forceinline__ float wave_scan_incl(float x) {
    float f = x;
    {
        int t_ = __builtin_amdgcn_update_dpp(0, __float_as_int(f), 0x111, 0xf, 0xf, false);
        f += __int_as_float(t_);
    }
    {
        int t_ = __builtin_amdgcn_update_dpp(0, __float_as_int(f), 0x112, 0xf, 0xf, false);
        f += __int_as_float(t_);
    }
    {
        int t_ = __builtin_amdgcn_update_dpp(0, __float_as_int(f), 0x114, 0xf, 0xf, false);
        f += __int_as_float(t_);
    }
    {
        int t_ = __builtin_amdgcn_update_dpp(0, __float_as_int(f), 0x118, 0xf, 0xf, false);
        f += __int_as_float(t_);
    }
    {
        int t_ = __builtin_amdgcn_update_dpp(0, __float_as_int(f), 0x142, 0xa, 0xf, false);
        f += __int_as_float(t_);
    }
    {
        int t_ = __builtin_amdgcn_update_dpp(0, __float_as_int(f), 0x143, 0xc, 0xf, false);
        f += __int_as_float(t_);
    }
    return f;
}

__device__ __forceinline__ float readlane63(float x) {
    return __int_as_float(__builtin_amdgcn_readlane(__float_as_int(x), 63));
}
}

__global__ __launch_bounds__(NT, 8) void fs2_avg_kernel(
    const float* __restrict__ frame_scalar,
    const float* __restrict__ duration,
    const int* __restrict__ frame_scalar_len,
    const int* __restrict__ duration_len,
    float* __restrict__ out,
    int n_rows)
{
    __shared__ alignas(16) float s_S[TF];   // wave-local inclusive prefix
    __shared__ alignas(16) float s_wA[NW];  // duration wave totals
    __shared__ alignas(16) float s_wF[NW];  // frame wave totals

    const int b = blockIdx.x;
    const int t = threadIdx.x;
    const int lane = t & 63;
    const int wid = t >> 6;

    const int dlen = duration_len[b];
    const int flen_i = frame_scalar_len[b];
    const float flen = (float)flen_i;

    const float* frow = frame_scalar + (size_t)b * TF;

    // Entry-time bound on consumed frames: Sum(round(dur)) <= 16*dlen.
    const int UB = min(16 * dlen, flen_i);

    // Output 1: duration_len passthrough (independent; issue early)
    if (t == 0) out[(size_t)n_rows * TT + b] = (float)dlen;

    // ---- duration load (predicated), issued first (scan is critical path) ----
    const int j0 = t * 2;
    float2 d2 = (j0 < dlen)
        ? *reinterpret_cast<const float2*>(duration + (size_t)b * TT + j0)
        : make_float2(0.f, 0.f);

    // ---- coalesced frame loads at ENTRY, predicated at UB ----
    const int qb = 256 * wid + lane;        // quad index for j=0
    float4 v0 = make_float4(0.f, 0.f, 0.f, 0.f);
    float4 v1 = v0, v2 = v0, v3 = v0;
    if (4 * (qb)       < UB) v0 = *reinterpret_cast<const float4*>(frow + 4 * (qb));
    if (4 * (qb + 64)  < UB) v1 = *reinterpret_cast<const float4*>(frow + 4 * (qb + 64));
    if (4 * (qb + 128) < UB) v2 = *reinterpret_cast<const float4*>(frow + 4 * (qb + 128));
    if (4 * (qb + 192) < UB) v3 = *reinterpret_cast<const float4*>(frow + 4 * (qb + 192));

    // ---- duration round/clamp/mask + wave scan (frame loads in flight) ----
    float d0 = fmaxf(rintf(d2.x), 0.0f);
    float d1 = fmaxf(rintf(d2.y), 0.0f);
    if (j0 + 1 >= dlen) d1 = 0.0f;   // covers j0 >= dlen too (d2 = 0 there)
    const float c0 = d0, c1 = c0 + d1;

    const float ws = wave_scan_incl(c1);
    if (lane == 63) s_wA[wid] = ws;

    __syncthreads();   // barrier #1: duration wave totals visible

    // ---- cross-wave duration base ----
    const float4 wA0 = *reinterpret_cast<const float4*>(&s_wA[0]);
    const float4 wA1 = *reinterpret_cast<const float4*>(&s_wA[4]);
    float base = ws - c1;   // exclusive duration prefix within wave
    base += (wid > 0) ? wA0.x : 0.f;
    base += (wid > 1) ? wA0.y : 0.f;
    base += (wid > 2) ? wA0.z : 0.f;
    base += (wid > 3) ? wA0.w : 0.f;
    base += (wid > 4) ? wA1.x : 0.f;
    base += (wid > 5) ? wA1.y : 0.f;
    base += (wid > 6) ? wA1.z : 0.f;

    // ---- token boundaries (VALU, overlaps any residual load latency) ----
    const float sprev0 = (j0 == 0) ? 0.0f : fminf(base, flen);
    const float e0 = fminf(base + c0, flen);
    const float e1 = fminf(base + c1, flen);
    const int si = (int)sprev0;
    const int mi = (int)e0;
    const int ei = (int)e1;

    // ---- per-quad inclusive prefixes (in regs; waitcnt lands here) ----
    float p0[4], p1[4], p2[4], p3[4];
    p0[0] = v0.x; p0[1] = p0[0] + v0.y; p0[2] = p0[1] + v0.z; p0[3] = p0[2] + v0.w;
    p1[0] = v1.x; p1[1] = p1[0] + v1.y; p1[2] = p1[1] + v1.z; p1[3] = p1[2] + v1.w;
    p2[0] = v2.x; p2[1] = p2[0] + v2.y; p2[2] = p2[1] + v2.z; p2[3] = p2[2] + v2.w;
    p3[0] = v3.x; p3[1] = p3[0] + v3.y; p3[2] = p3[1] + v3.z; p3[3] = p3[2] + v3.w;

    // ---- 4 independent wave64 scans over quad sums (DPP, good ILP) ----
    const float f0s = wave_scan_incl(p0[3]);
    const float f1s = wave_scan_incl(p1[3]);
    const float f2s = wave_scan_incl(p2[3]);
    const float f3s = wave_scan_incl(p3[3]);

    const float T0 = readlane63(f0s);
    const float T1 = readlane63(f1s);
    const float T2 = readlane63(f2s);
    const float T3 = readlane63(f3s);
    const float Cc1 = T0, Cc2 = T0 + T1, Cc3 = Cc2 + T2;
    const float Fw = Cc3 + T3;              // wave frame total

    // ---- WAVE-LOCAL inclusive prefix -> linear LDS (lane-contiguous b128) ----
    {
        const float eb0 =       (f0s - p0[3]);
        const float eb1 = Cc1 + (f1s - p1[3]);
        const float eb2 = Cc2 + (f2s - p2[3]);
        const float eb3 = Cc3 + (f3s - p3[3]);
        *reinterpret_cast<float4*>(&s_S[4 * (qb)]) =
            make_float4(eb0 + p0[0], eb0 + p0[1], eb0 + p0[2], eb0 + p0[3]);
        *reinterpret_cast<float4*>(&s_S[4 * (qb + 64)]) =
            make_float4(eb1 + p1[0], eb1 + p1[1], eb1 + p1[2], eb1 + p1[3]);
        *reinterpret_cast<float4*>(&s_S[4 * (qb + 128)]) =
            make_float4(eb2 + p2[0], eb2 + p2[1], eb2 + p2[2], eb2 + p2[3]);
        *reinterpret_cast<float4*>(&s_S[4 * (qb + 192)]) =
            make_float4(eb3 + p3[0], eb3 + p3[1], eb3 + p3[2], eb3 + p3[3]);
    }
    if (lane == 63) s_wF[wid] = Fw;

    __syncthreads();   // barrier #2: prefix + frame wave totals visible

    // ---- gather with cross-wave correction FBc(owning wave) ----
    const float4 wF0 = *reinterpret_cast<const float4*>(&s_wF[0]);
    const float4 wF1 = *reinterpret_cast<const float4*>(&s_wF[4]);

    float o0 = 0.0f, o1 = 0.0f;
    if (ei > si) {
        auto G = [&](int idx) -> float {   // idx >= 1 guaranteed by callers
            const int i = idx - 1;
            const int w = i >> 10;         // 1024 frames per wave chunk
            float s = s_S[i];
            s += (w > 0) ? wF0.x : 0.f;
            s += (w > 1) ? wF0.y : 0.f;
            s += (w > 2) ? wF0.z : 0.f;
            s += (w > 3) ? wF0.w : 0.f;
            s += (w > 4) ? wF1.x : 0.f;
            s += (w > 5) ? wF1.y : 0.f;
            s += (w > 6) ? wF1.z : 0.f;
            return s;
        };
        const float Gs = (si == 0) ? 0.0f : G(si);
        const float Gm = (mi == 0) ? 0.0f : G(mi);
        const float Ge = G(ei);             // ei > si >= 0 -> ei >= 1
        o0 = (mi > si) ? (Gm - Gs) * __builtin_amdgcn_rcpf(e0 - sprev0) : 0.0f;
        o1 = (ei > mi) ? (Ge - Gm) * __builtin_amdgcn_rcpf(e1 - e0) : 0.0f;
    }

    *reinterpret_cast<float2*>(out + (size_t)b * TT + j0) = make_float2(o0, o1);
}

extern "C" void kernel_launch(void* const* d_in, const int* in_sizes, int n_in,
                              void* d_out, int out_size, void* d_ws, size_t ws_size,
                              hipStream_t stream) {
    const float* frame_scalar     = (const float*)d_in[0];
    const float* duration         = (const float*)d_in[1];
    const int*   frame_scalar_len = (const int*)d_in[2];
    const int*   duration_len     = (const int*)d_in[3];
    float* out = (float*)d_out;
    const int B = in_sizes[2];   // frame_scalar_len has B elements
    fs2_avg_kernel<<<B, NT, 0, stream>>>(frame_scalar, duration, frame_scalar_len,
                                         duration_len, out, B);
}

// Round 7
// 12.965 us; speedup vs baseline: 1.0427x; 1.0427x over previous
//
#include <hip/hip_runtime.h>

// FastSpeech2 hard duration-based frame->token averaging.
// R15 = R13 verbatim (revert of R14). Series conclusion: measured time =
// ~8us structure-invariant fixed term (launch/measurement overhead; survived
// five different inner structures R8..R14) + mandatory traffic (~35MB:
// 22.4MB exact-Fneed frame reads + 4.2MB duration + 8.4MB output) streaming
// at ~peak marginal BW (R12->R13: -10.6MB = -1.31us; R13->R14: +5.3MB =
// +0.52us). R14 proved chain exposure is fully hidden by TLP (entry-issued
// loads at +5.3MB regressed), so exact-Fneed predication (R13) dominates.
//  - dur scan first; barrier #1 -> Fneed = min(sum(dur), flen); frame loads
//    predicated at Fneed (the traffic cut).
//  - coalesced wave-chunk loads, reg prefix, 4 DPP scans, wave-local
//    linear-LDS prefix (no swizzle, no conflicts), cross-wave correction
//    folded into the 3-point gather, 2 barriers total.
// Output = [B*TT token_scalar | B duration_len(float)].

namespace {
constexpr int TT = 1024;   // tokens per row
constexpr int TF = 8192;   // frames per row
constexpr int NT = 512;    // threads per block (8 waves)
constexpr int NW = NT / 64;

// Canonical GCN wave64 inclusive add-scan via DPP (VALU pipe, no LDS).
__device__ __forceinline__ float wave_scan_incl(float x) {
    float f = x;
    {
        int t_ = __builtin_amdgcn_update_dpp(0, __float_as_int(f), 0x111, 0xf, 0xf, false);
        f += __int_as_float(t_);
    }
    {
        int t_ = __builtin_amdgcn_update_dpp(0, __float_as_int(f), 0x112, 0xf, 0xf, false);
        f += __int_as_float(t_);
    }
    {
        int t_ = __builtin_amdgcn_update_dpp(0, __float_as_int(f), 0x114, 0xf, 0xf, false);
        f += __int_as_float(t_);
    }
    {
        int t_ = __builtin_amdgcn_update_dpp(0, __float_as_int(f), 0x118, 0xf, 0xf, false);
        f += __int_as_float(t_);
    }
    {
        int t_ = __builtin_amdgcn_update_dpp(0, __float_as_int(f), 0x142, 0xa, 0xf, false);
        f += __int_as_float(t_);
    }
    {
        int t_ = __builtin_amdgcn_update_dpp(0, __float_as_int(f), 0x143, 0xc, 0xf, false);
        f += __int_as_float(t_);
    }
    return f;
}

__device__ __forceinline__ float readlane63(float x) {
    return __int_as_float(__builtin_amdgcn_readlane(__float_as_int(x), 63));
}
}

__global__ __launch_bounds__(NT, 8) void fs2_avg_kernel(
    const float* __restrict__ frame_scalar,
    const float* __restrict__ duration,
    const int* __restrict__ frame_scalar_len,
    const int* __restrict__ duration_len,
    float* __restrict__ out,
    int n_rows)
{
    __shared__ alignas(16) float s_S[TF];   // wave-local inclusive prefix
    __shared__ alignas(16) float s_wA[NW];  // duration wave totals
    __shared__ alignas(16) float s_wF[NW];  // frame wave totals

    const int b = blockIdx.x;
    const int t = threadIdx.x;
    const int lane = t & 63;
    const int wid = t >> 6;

    const int dlen = duration_len[b];
    const int flen_i = frame_scalar_len[b];
    const float flen = (float)flen_i;

    const float* frow = frame_scalar + (size_t)b * TF;

    // Output 1: duration_len passthrough (independent; issue early)
    if (t == 0) out[(size_t)n_rows * TT + b] = (float)dlen;

    // ---- duration load (predicated) + round/clamp/mask ----
    const int j0 = t * 2;
    float2 d2 = (j0 < dlen)
        ? *reinterpret_cast<const float2*>(duration + (size_t)b * TT + j0)
        : make_float2(0.f, 0.f);
    float d0 = fmaxf(rintf(d2.x), 0.0f);
    float d1 = fmaxf(rintf(d2.y), 0.0f);
    if (j0 + 1 >= dlen) d1 = 0.0f;   // covers j0 >= dlen too (d2 = 0 there)
    const float c0 = d0, c1 = c0 + d1;

    // ---- duration wave scan ----
    const float ws = wave_scan_incl(c1);
    if (lane == 63) s_wA[wid] = ws;

    __syncthreads();   // barrier #1: duration wave totals visible

    // ---- cross-wave duration base + block total ----
    const float4 wA0 = *reinterpret_cast<const float4*>(&s_wA[0]);
    const float4 wA1 = *reinterpret_cast<const float4*>(&s_wA[4]);
    float base = ws - c1;   // exclusive duration prefix within wave
    base += (wid > 0) ? wA0.x : 0.f;
    base += (wid > 1) ? wA0.y : 0.f;
    base += (wid > 2) ? wA0.z : 0.f;
    base += (wid > 3) ? wA0.w : 0.f;
    base += (wid > 4) ? wA1.x : 0.f;
    base += (wid > 5) ? wA1.y : 0.f;
    base += (wid > 6) ? wA1.z : 0.f;

    const float total = wA0.x + wA0.y + wA0.z + wA0.w
                      + wA1.x + wA1.y + wA1.z + wA1.w;
    const int Fneed_i = (int)fminf(total, flen);   // frames actually consumed

    // ---- coalesced frame loads, predicated at Fneed (the traffic cut) ----
    const int qb = 256 * wid + lane;        // quad index for j=0
    float4 v0 = make_float4(0.f, 0.f, 0.f, 0.f);
    float4 v1 = v0, v2 = v0, v3 = v0;
    if (4 * (qb)       < Fneed_i) v0 = *reinterpret_cast<const float4*>(frow + 4 * (qb));
    if (4 * (qb + 64)  < Fneed_i) v1 = *reinterpret_cast<const float4*>(frow + 4 * (qb + 64));
    if (4 * (qb + 128) < Fneed_i) v2 = *reinterpret_cast<const float4*>(frow + 4 * (qb + 128));
    if (4 * (qb + 192) < Fneed_i) v3 = *reinterpret_cast<const float4*>(frow + 4 * (qb + 192));

    // ---- token boundaries (VALU, overlaps frame-load latency) ----
    const float sprev0 = (j0 == 0) ? 0.0f : fminf(base, flen);
    const float e0 = fminf(base + c0, flen);
    const float e1 = fminf(base + c1, flen);
    const int si = (int)sprev0;
    const int mi = (int)e0;
    const int ei = (int)e1;

    // ---- per-quad inclusive prefixes (in regs) ----
    float p0[4], p1[4], p2[4], p3[4];
    p0[0] = v0.x; p0[1] = p0[0] + v0.y; p0[2] = p0[1] + v0.z; p0[3] = p0[2] + v0.w;
    p1[0] = v1.x; p1[1] = p1[0] + v1.y; p1[2] = p1[1] + v1.z; p1[3] = p1[2] + v1.w;
    p2[0] = v2.x; p2[1] = p2[0] + v2.y; p2[2] = p2[1] + v2.z; p2[3] = p2[2] + v2.w;
    p3[0] = v3.x; p3[1] = p3[0] + v3.y; p3[2] = p3[1] + v3.z; p3[3] = p3[2] + v3.w;

    // ---- 4 independent wave64 scans over quad sums (DPP, good ILP) ----
    const float f0s = wave_scan_incl(p0[3]);
    const float f1s = wave_scan_incl(p1[3]);
    const float f2s = wave_scan_incl(p2[3]);
    const float f3s = wave_scan_incl(p3[3]);

    const float T0 = readlane63(f0s);
    const float T1 = readlane63(f1s);
    const float T2 = readlane63(f2s);
    const float T3 = readlane63(f3s);
    const float Cc1 = T0, Cc2 = T0 + T1, Cc3 = Cc2 + T2;
    const float Fw = Cc3 + T3;              // wave frame total

    // ---- WAVE-LOCAL inclusive prefix -> linear LDS (lane-contiguous b128) ----
    {
        const float eb0 =       (f0s - p0[3]);
        const float eb1 = Cc1 + (f1s - p1[3]);
        const float eb2 = Cc2 + (f2s - p2[3]);
        const float eb3 = Cc3 + (f3s - p3[3]);
        *reinterpret_cast<float4*>(&s_S[4 * (qb)]) =
            make_float4(eb0 + p0[0], eb0 + p0[1], eb0 + p0[2], eb0 + p0[3]);
        *reinterpret_cast<float4*>(&s_S[4 * (qb + 64)]) =
            make_float4(eb1 + p1[0], eb1 + p1[1], eb1 + p1[2], eb1 + p1[3]);
        *reinterpret_cast<float4*>(&s_S[4 * (qb + 128)]) =
            make_float4(eb2 + p2[0], eb2 + p2[1], eb2 + p2[2], eb2 + p2[3]);
        *reinterpret_cast<float4*>(&s_S[4 * (qb + 192)]) =
            make_float4(eb3 + p3[0], eb3 + p3[1], eb3 + p3[2], eb3 + p3[3]);
    }
    if (lane == 63) s_wF[wid] = Fw;

    __syncthreads();   // barrier #2: prefix + frame wave totals visible

    // ---- gather with cross-wave correction FBc(owning wave) ----
    const float4 wF0 = *reinterpret_cast<const float4*>(&s_wF[0]);
    const float4 wF1 = *reinterpret_cast<const float4*>(&s_wF[4]);

    float o0 = 0.0f, o1 = 0.0f;
    if (ei > si) {
        auto G = [&](int idx) -> float {   // idx >= 1 guaranteed by callers
            const int i = idx - 1;
            const int w = i >> 10;         // 1024 frames per wave chunk
            float s = s_S[i];
            s += (w > 0) ? wF0.x : 0.f;
            s += (w > 1) ? wF0.y : 0.f;
            s += (w > 2) ? wF0.z : 0.f;
            s += (w > 3) ? wF0.w : 0.f;
            s += (w > 4) ? wF1.x : 0.f;
            s += (w > 5) ? wF1.y : 0.f;
            s += (w > 6) ? wF1.z : 0.f;
            return s;
        };
        const float Gs = (si == 0) ? 0.0f : G(si);
        const float Gm = (mi == 0) ? 0.0f : G(mi);
        const float Ge = G(ei);             // ei > si >= 0 -> ei >= 1
        o0 = (mi > si) ? (Gm - Gs) * __builtin_amdgcn_rcpf(e0 - sprev0) : 0.0f;
        o1 = (ei > mi) ? (Ge - Gm) * __builtin_amdgcn_rcpf(e1 - e0) : 0.0f;
    }

    *reinterpret_cast<float2*>(out + (size_t)b * TT + j0) = make_float2(o0, o1);
}

extern "C" void kernel_launch(void* const* d_in, const int* in_sizes, int n_in,
                              void* d_out, int out_size, void* d_ws, size_t ws_size,
                              hipStream_t stream) {
    const float* frame_scalar     = (const float*)d_in[0];
    const float* duration         = (const float*)d_in[1];
    const int*   frame_scalar_len = (const int*)d_in[2];
    const int*   duration_len     = (const int*)d_in[3];
    float* out = (float*)d_out;
    const int B = in_sizes[2];   // frame_scalar_len has B elements
    fs2_avg_kernel<<<B, NT, 0, stream>>>(frame_scalar, duration, frame_scalar_len,
                                         duration_len, out, B);
}